// Round 8
// baseline (638.497 us; speedup 1.0000x reference)
//
#include <hip/hip_runtime.h>

#define NN 100000
#define NE 1600000

// ---------------------------------------------------------------------------
// Workspace layout in 4-byte units (~92 MB total; proven available)
// ---------------------------------------------------------------------------
#define OFF_M    0                         // 128*128 folded [A | wu1_top]
#define OFF_B    (OFF_M + 16384)           // 32*64   we @ wm1_bot
#define OFF_C    (OFF_B + 2048)            // 64      folded msg bias
#define OFF_W2U  (OFF_C + 64)              // 64*64   wm2 @ wu1_bot
#define OFF_D2   (OFF_W2U + 4096)          // 64      bm2 @ wu1_bot
#define OFF_BSUM (OFF_D2 + 64)             // 128 block sums (scan)
#define OFF_BOFF (OFF_BSUM + 128)          // 128 block offsets (scan)
#define OFF_PRA  (OFF_BOFF + 128)          // NN*64
#define OFF_PRU  (OFF_PRA + NN * 64)       // NN*64
#define OFF_H    (OFF_PRU + NN * 64)       // NN*64  (agg in fallback)
#define OFF_HIST (OFF_H + NN * 64)         // NN
#define OFF_CUR  (OFF_HIST + NN)           // NN
#define OFF_STRT (OFF_CUR + NN)            // NN+1 (+pad)
#define OFF_ESRC (OFF_STRT + NN + 4)       // NE int2 {edge, src} sorted by dst
#define WS_UNITS (OFF_ESRC + 2 * NE)

__device__ __forceinline__ int rfl(int x) {
  return __builtin_amdgcn_readfirstlane(x);
}

// ---------------------------------------------------------------------------
// Weight folding:
//   M[128][128]: cols 0-63 = wn@wm1_top ; cols 64-127 = wu1[0:128,:]
//   B[32][64] = we@wm1_bot ; c = bm1 + bn@wm1_top + be@wm1_bot
//   W2U[64][64] = wm2 @ wu1_bot ; d2 = bm2 @ wu1_bot
// ---------------------------------------------------------------------------
__global__ __launch_bounds__(256) void k_fold(
    const float* __restrict__ wn, const float* __restrict__ bn,
    const float* __restrict__ we, const float* __restrict__ be,
    const float* __restrict__ wm1, const float* __restrict__ bm1,
    const float* __restrict__ wm2, const float* __restrict__ bm2,
    const float* __restrict__ wu1,
    float* __restrict__ M, float* __restrict__ B, float* __restrict__ c,
    float* __restrict__ W2U, float* __restrict__ d2) {
  int t = blockIdx.x * 256 + threadIdx.x;
  if (t < 16384) {
    int k = t >> 7, j = t & 127;
    float acc;
    if (j < 64) {
      acc = 0.f;
      for (int h = 0; h < 64; ++h) acc += wn[k * 64 + h] * wm1[h * 64 + j];
    } else {
      acc = wu1[k * 64 + (j - 64)];
    }
    M[t] = acc;
  } else if (t < 16384 + 2048) {
    int u = t - 16384;
    int k = u >> 6, j = u & 63;
    float acc = 0.f;
    for (int h = 0; h < 64; ++h) acc += we[k * 64 + h] * wm1[(64 + h) * 64 + j];
    B[u] = acc;
  } else if (t < 16384 + 2048 + 64) {
    int j = t - (16384 + 2048);
    float acc = bm1[j];
    for (int h = 0; h < 64; ++h)
      acc += bn[h] * wm1[h * 64 + j] + be[h] * wm1[(64 + h) * 64 + j];
    c[j] = acc;
  } else if (t < 16384 + 2048 + 64 + 4096) {
    int u = t - (16384 + 2048 + 64);
    int k = u >> 6, j = u & 63;
    float acc = 0.f;
    for (int h = 0; h < 64; ++h) acc += wm2[k * 64 + h] * wu1[(128 + h) * 64 + j];
    W2U[u] = acc;
  } else if (t < 16384 + 2048 + 64 + 4096 + 64) {
    int j = t - (16384 + 2048 + 64 + 4096);
    float acc = 0.f;
    for (int h = 0; h < 64; ++h) acc += bm2[h] * wu1[(128 + h) * 64 + j];
    d2[j] = acc;
  }
}

// ---------------------------------------------------------------------------
// PRA[n] = nf[n]@A ; PRU[n] = nf[n]@wu1_top  (lane-per-node, scalar weights)
// ---------------------------------------------------------------------------
__global__ __launch_bounds__(256) void k_node(
    const float* __restrict__ nf, const float* __restrict__ M,
    float* __restrict__ PRA, float* __restrict__ PRU) {
  int n = blockIdx.x * 256 + threadIdx.x;
  if (n >= NN) return;
  const float* __restrict__ row = &nf[(size_t)n * 128];
#pragma unroll 1
  for (int jc = 0; jc < 128; jc += 32) {
    float q[32];
#pragma unroll
    for (int jj = 0; jj < 32; ++jj) q[jj] = 0.f;
#pragma unroll 4
    for (int k = 0; k < 128; k += 4) {
      float4 r4 = *(const float4*)&row[k];
#pragma unroll
      for (int jj = 0; jj < 32; ++jj) q[jj] += r4.x * M[(k + 0) * 128 + jc + jj];
#pragma unroll
      for (int jj = 0; jj < 32; ++jj) q[jj] += r4.y * M[(k + 1) * 128 + jc + jj];
#pragma unroll
      for (int jj = 0; jj < 32; ++jj) q[jj] += r4.z * M[(k + 2) * 128 + jc + jj];
#pragma unroll
      for (int jj = 0; jj < 32; ++jj) q[jj] += r4.w * M[(k + 3) * 128 + jc + jj];
    }
    float* dstp = (jc < 64) ? &PRA[(size_t)n * 64 + jc] : &PRU[(size_t)n * 64 + (jc - 64)];
#pragma unroll
    for (int jj = 0; jj < 32; jj += 4)
      *(float4*)&dstp[jj] = make_float4(q[jj], q[jj + 1], q[jj + 2], q[jj + 3]);
  }
}

// ---------------------------------------------------------------------------
// Counting sort: hist -> 3-phase scan -> scatter {edge,src} pairs
// ---------------------------------------------------------------------------
__global__ __launch_bounds__(256) void k_hist(const int* __restrict__ idx,
                                              int* __restrict__ hist) {
  int e = blockIdx.x * 256 + threadIdx.x;
  if (e < NE) atomicAdd(&hist[idx[NE + e]], 1);
}

__global__ __launch_bounds__(1024) void k_scanA(const int* __restrict__ hist,
                                                int* __restrict__ strt,
                                                int* __restrict__ bsum) {
  __shared__ int lds[1024];
  int t = threadIdx.x;
  int i = blockIdx.x * 1024 + t;
  int v = (i < NN) ? hist[i] : 0;
  lds[t] = v;
  __syncthreads();
  for (int off = 1; off < 1024; off <<= 1) {
    int u = (t >= off) ? lds[t - off] : 0;
    __syncthreads();
    lds[t] += u;
    __syncthreads();
  }
  if (i < NN) strt[i] = lds[t] - v;
  if (t == 1023) bsum[blockIdx.x] = lds[1023];
}

__global__ __launch_bounds__(128) void k_scanB(const int* __restrict__ bsum,
                                               int* __restrict__ boff,
                                               int* __restrict__ strt,
                                               int nblocks) {
  __shared__ int lds[128];
  int t = threadIdx.x;
  int v = (t < nblocks) ? bsum[t] : 0;
  lds[t] = v;
  __syncthreads();
  for (int off = 1; off < 128; off <<= 1) {
    int u = (t >= off) ? lds[t - off] : 0;
    __syncthreads();
    lds[t] += u;
    __syncthreads();
  }
  if (t < nblocks) boff[t] = lds[t] - v;
  if (t == 127) strt[NN] = lds[127];
}

__global__ __launch_bounds__(1024) void k_scanC(int* __restrict__ strt,
                                                const int* __restrict__ boff) {
  int i = blockIdx.x * 1024 + threadIdx.x;
  if (i < NN) strt[i] += boff[blockIdx.x];
}

__global__ __launch_bounds__(256) void k_scatter_pairs2(
    const int* __restrict__ idx, const int* __restrict__ strt,
    int* __restrict__ cursor, int2* __restrict__ esrc) {
  int e = blockIdx.x * 256 + threadIdx.x;
  if (e >= NE) return;
  int dst = idx[NE + e];
  int pos = atomicAdd(&cursor[dst], 1);
  int2 v;
  v.x = e;
  v.y = idx[e];
  esrc[strt[dst] + pos] = v;
}

// ---------------------------------------------------------------------------
// Fused message+aggregate v3: one WAVE per node, lane = output dim.
// ef row address is wave-uniform (readfirstlane'd edge id) -> compiler emits
// s_load; the 32-float row lives in SGPRs and feeds v_fmac_f32 v,s,v.
// No LDS. Manual 2x-unrolled ping-pong (rA/rB) = 1-deep prefetch of next
// edge's row + PRA. 4 split accumulators break the fmac chain.
// ---------------------------------------------------------------------------
#define LOAD_ROW(dst, pr, sidx)                                   \
  {                                                               \
    int2 es_ = esrc[sidx];                                        \
    int e_ = rfl(es_.x), sr_ = rfl(es_.y);                        \
    const float* __restrict__ ep_ = &ef[(size_t)e_ * 32];         \
    _Pragma("unroll") for (int k_ = 0; k_ < 32; ++k_)             \
        dst[k_] = ep_[k_];                                        \
    pr = PRA[(size_t)sr_ * 64 + lane];                            \
  }

#define EDGE_FMA(row, pr)                                         \
  {                                                               \
    float q0 = cl, q1 = 0.f, q2 = 0.f, q3 = 0.f;                  \
    _Pragma("unroll") for (int k_ = 0; k_ < 32; k_ += 4) {        \
      q0 = fmaf(row[k_ + 0], Bcol[k_ + 0], q0);                   \
      q1 = fmaf(row[k_ + 1], Bcol[k_ + 1], q1);                   \
      q2 = fmaf(row[k_ + 2], Bcol[k_ + 2], q2);                   \
      q3 = fmaf(row[k_ + 3], Bcol[k_ + 3], q3);                   \
    }                                                             \
    acc += fmaxf((q0 + q1) + (q2 + q3) + pr, 0.f);                \
  }

__global__ __launch_bounds__(256) void k_gather5(
    const int2* __restrict__ esrc, const int* __restrict__ strt,
    const float* __restrict__ ef, const float* __restrict__ Bm,
    const float* __restrict__ c, const float* __restrict__ PRA,
    float* __restrict__ H) {
  int wib = threadIdx.x >> 6;
  int lane = threadIdx.x & 63;
  int n = rfl(blockIdx.x * 4 + wib);
  if (n >= NN) return;

  float Bcol[32];
#pragma unroll
  for (int k = 0; k < 32; ++k) Bcol[k] = Bm[k * 64 + lane];
  float cl = c[lane];

  int s0 = rfl(strt[n]);
  int s1 = rfl(strt[n + 1]);
  float acc = 0.f;

  float rA[32], rB[32];
  float prA = 0.f, prB = 0.f;

  if (s0 < s1) LOAD_ROW(rA, prA, s0);

  int s = s0;
#pragma unroll 1
  while (s + 1 < s1) {
    LOAD_ROW(rB, prB, s + 1);      // prefetch edge s+1
    EDGE_FMA(rA, prA);             // compute edge s
    if (s + 2 < s1) LOAD_ROW(rA, prA, s + 2);  // prefetch edge s+2
    EDGE_FMA(rB, prB);             // compute edge s+1
    s += 2;
  }
  if (s < s1) EDGE_FMA(rA, prA);   // tail odd edge

  H[(size_t)n * 64 + lane] = acc;
}

// ---------------------------------------------------------------------------
// Final per-node MLP with W2U fold:
//   pre = PRU[n] + H[n]@W2U + deg*d2 + bu1 ; out = relu(pre)@wu2 + bu2
// ---------------------------------------------------------------------------
__global__ __launch_bounds__(256) void k_update3(
    const float* __restrict__ H, const int* __restrict__ strt,
    const float* __restrict__ PRU,
    const float* __restrict__ W2U, const float* __restrict__ d2,
    const float* __restrict__ bu1,
    const float* __restrict__ wu2, const float* __restrict__ bu2,
    float* __restrict__ out) {
  int n = blockIdx.x * 256 + threadIdx.x;
  if (n >= NN) return;

  float Hr[64];
#pragma unroll
  for (int k = 0; k < 64; k += 4)
    *(float4*)&Hr[k] = *(const float4*)&H[(size_t)n * 64 + k];
  float deg = (float)(strt[n + 1] - strt[n]);

  float acc[64];
#pragma unroll
  for (int o = 0; o < 64; ++o) acc[o] = bu2[o];

  const float* __restrict__ prs = &PRU[(size_t)n * 64];
#pragma unroll 1
  for (int jc = 0; jc < 64; jc += 16) {
    float q[16];
#pragma unroll
    for (int jj = 0; jj < 16; ++jj) q[jj] = bu1[jc + jj] + deg * d2[jc + jj];
#pragma unroll
    for (int k = 0; k < 64; ++k) {
      float hv = Hr[k];
#pragma unroll
      for (int jj = 0; jj < 16; ++jj) q[jj] += hv * W2U[k * 64 + jc + jj];
    }
#pragma unroll
    for (int jj = 0; jj < 16; ++jj) {
      float h = fmaxf(prs[jc + jj] + q[jj], 0.f);
#pragma unroll
      for (int o = 0; o < 64; ++o) acc[o] += h * wu2[(jc + jj) * 64 + o];
    }
  }

#pragma unroll
  for (int o = 0; o < 64; o += 4)
    *(float4*)&out[(size_t)n * 64 + o] = make_float4(acc[o], acc[o + 1], acc[o + 2], acc[o + 3]);
}

// ---------------------------------------------------------------------------
// Fallback (ws too small): round-1 atomic scatter path
// ---------------------------------------------------------------------------
__global__ __launch_bounds__(256) void k_edge_at(
    const int* __restrict__ idx, const float* __restrict__ ef,
    const float* __restrict__ B, const float* __restrict__ c,
    const float* __restrict__ wm2, const float* __restrict__ bm2,
    const float* __restrict__ PRA, float* __restrict__ agg) {
  int e = blockIdx.x * 256 + threadIdx.x;
  if (e >= NE) return;
  int src = idx[e];
  int dst = idx[NE + e];
  float efr[32];
#pragma unroll
  for (int k = 0; k < 32; k += 4)
    *(float4*)&efr[k] = *(const float4*)&ef[(size_t)e * 32 + k];
  float m[64];
#pragma unroll
  for (int o = 0; o < 64; ++o) m[o] = bm2[o];
  const float* __restrict__ prs = &PRA[(size_t)src * 64];
#pragma unroll 1
  for (int jc = 0; jc < 64; jc += 16) {
    float q[16];
#pragma unroll
    for (int jj = 0; jj < 16; ++jj) q[jj] = c[jc + jj];
#pragma unroll
    for (int k = 0; k < 32; ++k) {
      float ev = efr[k];
#pragma unroll
      for (int jj = 0; jj < 16; ++jj) q[jj] += ev * B[k * 64 + jc + jj];
    }
#pragma unroll
    for (int jj = 0; jj < 16; ++jj) {
      float h = fmaxf(prs[jc + jj] + q[jj], 0.f);
#pragma unroll
      for (int o = 0; o < 64; ++o) m[o] += h * wm2[(jc + jj) * 64 + o];
    }
  }
  float* __restrict__ ap = &agg[(size_t)dst * 64];
#pragma unroll
  for (int o = 0; o < 64; ++o) atomicAdd(&ap[o], m[o]);
}

__global__ __launch_bounds__(256) void k_update_at(
    const float* __restrict__ agg, const float* __restrict__ PRU,
    const float* __restrict__ wu1, const float* __restrict__ bu1,
    const float* __restrict__ wu2, const float* __restrict__ bu2,
    float* __restrict__ out) {
  int n = blockIdx.x * 256 + threadIdx.x;
  if (n >= NN) return;
  float ar[64];
#pragma unroll
  for (int k = 0; k < 64; k += 4)
    *(float4*)&ar[k] = *(const float4*)&agg[(size_t)n * 64 + k];
  float acc[64];
#pragma unroll
  for (int o = 0; o < 64; ++o) acc[o] = bu2[o];
  const float* __restrict__ prs = &PRU[(size_t)n * 64];
#pragma unroll 1
  for (int jc = 0; jc < 64; jc += 16) {
    float q[16];
#pragma unroll
    for (int jj = 0; jj < 16; ++jj) q[jj] = bu1[jc + jj];
#pragma unroll
    for (int k = 0; k < 64; ++k) {
      float av = ar[k];
#pragma unroll
      for (int jj = 0; jj < 16; ++jj) q[jj] += av * wu1[(128 + k) * 64 + jc + jj];
    }
#pragma unroll
    for (int jj = 0; jj < 16; ++jj) {
      float h = fmaxf(prs[jc + jj] + q[jj], 0.f);
#pragma unroll
      for (int o = 0; o < 64; ++o) acc[o] += h * wu2[(jc + jj) * 64 + o];
    }
  }
#pragma unroll
  for (int o = 0; o < 64; o += 4)
    *(float4*)&out[(size_t)n * 64 + o] = make_float4(acc[o], acc[o + 1], acc[o + 2], acc[o + 3]);
}

extern "C" void kernel_launch(void* const* d_in, const int* in_sizes, int n_in,
                              void* d_out, int out_size, void* d_ws, size_t ws_size,
                              hipStream_t stream) {
  const float* nf  = (const float*)d_in[0];
  const int*   idx = (const int*)d_in[1];
  const float* ef  = (const float*)d_in[2];
  const float* wn  = (const float*)d_in[3];
  const float* bn  = (const float*)d_in[4];
  const float* we  = (const float*)d_in[5];
  const float* be  = (const float*)d_in[6];
  const float* wm1 = (const float*)d_in[7];
  const float* bm1 = (const float*)d_in[8];
  const float* wm2 = (const float*)d_in[9];
  const float* bm2 = (const float*)d_in[10];
  const float* wu1 = (const float*)d_in[11];
  const float* bu1 = (const float*)d_in[12];
  const float* wu2 = (const float*)d_in[13];
  const float* bu2 = (const float*)d_in[14];
  float* out = (float*)d_out;

  float* ws   = (float*)d_ws;
  float* M    = ws + OFF_M;
  float* B    = ws + OFF_B;
  float* c    = ws + OFF_C;
  float* W2U  = ws + OFF_W2U;
  float* d2   = ws + OFF_D2;
  int*   bsum = (int*)(ws + OFF_BSUM);
  int*   boff = (int*)(ws + OFF_BOFF);
  float* PRA  = ws + OFF_PRA;
  float* PRU  = ws + OFF_PRU;
  float* H    = ws + OFF_H;
  int*   hist = (int*)(ws + OFF_HIST);
  int*   cur  = (int*)(ws + OFF_CUR);
  int*   strt = (int*)(ws + OFF_STRT);
  int2*  esrc = (int2*)(ws + OFF_ESRC);

  const int SCAN_BLOCKS = (NN + 1023) / 1024;  // 98

  k_fold<<<(16384 + 2048 + 64 + 4096 + 64 + 255) / 256, 256, 0, stream>>>(
      wn, bn, we, be, wm1, bm1, wm2, bm2, wu1, M, B, c, W2U, d2);
  k_node<<<(NN + 255) / 256, 256, 0, stream>>>(nf, M, PRA, PRU);

  if (ws_size >= (size_t)WS_UNITS * 4) {
    hipMemsetAsync(hist, 0, (size_t)2 * NN * sizeof(int), stream);
    k_hist<<<(NE + 255) / 256, 256, 0, stream>>>(idx, hist);
    k_scanA<<<SCAN_BLOCKS, 1024, 0, stream>>>(hist, strt, bsum);
    k_scanB<<<1, 128, 0, stream>>>(bsum, boff, strt, SCAN_BLOCKS);
    k_scanC<<<SCAN_BLOCKS, 1024, 0, stream>>>(strt, boff);
    k_scatter_pairs2<<<(NE + 255) / 256, 256, 0, stream>>>(idx, strt, cur, esrc);
    k_gather5<<<(NN + 3) / 4, 256, 0, stream>>>(esrc, strt, ef, B, c, PRA, H);
    k_update3<<<(NN + 255) / 256, 256, 0, stream>>>(
        H, strt, PRU, W2U, d2, bu1, wu2, bu2, out);
  } else {
    hipMemsetAsync(H, 0, (size_t)NN * 64 * sizeof(float), stream);
    k_edge_at<<<(NE + 255) / 256, 256, 0, stream>>>(idx, ef, B, c, wm2, bm2, PRA, H);
    k_update_at<<<(NN + 255) / 256, 256, 0, stream>>>(
        H, PRU, wu1, bu1, wu2, bu2, out);
  }
}

// Round 9
// 563.691 us; speedup vs baseline: 1.1327x; 1.1327x over previous
//
#include <hip/hip_runtime.h>

#define NN 100000
#define NE 1600000

// ---------------------------------------------------------------------------
// Workspace layout in 4-byte units (~92 MB total; proven available)
// ---------------------------------------------------------------------------
#define OFF_M    0                         // 128*128 folded [A | wu1_top]
#define OFF_B    (OFF_M + 16384)           // 32*64   we @ wm1_bot
#define OFF_C    (OFF_B + 2048)            // 64      folded msg bias
#define OFF_W2U  (OFF_C + 64)              // 64*64   wm2 @ wu1_bot
#define OFF_D2   (OFF_W2U + 4096)          // 64      bm2 @ wu1_bot
#define OFF_BSUM (OFF_D2 + 64)             // 128 block sums (scan)
#define OFF_BOFF (OFF_BSUM + 128)          // 128 block offsets (scan)
#define OFF_PRA  (OFF_BOFF + 128)          // NN*64
#define OFF_PRU  (OFF_PRA + NN * 64)       // NN*64
#define OFF_H    (OFF_PRU + NN * 64)       // NN*64  (agg in fallback)
#define OFF_HIST (OFF_H + NN * 64)         // NN
#define OFF_CUR  (OFF_HIST + NN)           // NN
#define OFF_STRT (OFF_CUR + NN)            // NN+1 (+pad)
#define OFF_ESRC (OFF_STRT + NN + 4)       // NE int2 {edge, src} sorted by dst
#define WS_UNITS (OFF_ESRC + 2 * NE)

__device__ __forceinline__ int rfl(int x) {
  return __builtin_amdgcn_readfirstlane(x);
}

// ---------------------------------------------------------------------------
// Weight folding:
//   M[128][128]: cols 0-63 = wn@wm1_top ; cols 64-127 = wu1[0:128,:]
//   B[32][64] = we@wm1_bot ; c = bm1 + bn@wm1_top + be@wm1_bot
//   W2U[64][64] = wm2 @ wu1_bot ; d2 = bm2 @ wu1_bot
// ---------------------------------------------------------------------------
__global__ __launch_bounds__(256) void k_fold(
    const float* __restrict__ wn, const float* __restrict__ bn,
    const float* __restrict__ we, const float* __restrict__ be,
    const float* __restrict__ wm1, const float* __restrict__ bm1,
    const float* __restrict__ wm2, const float* __restrict__ bm2,
    const float* __restrict__ wu1,
    float* __restrict__ M, float* __restrict__ B, float* __restrict__ c,
    float* __restrict__ W2U, float* __restrict__ d2) {
  int t = blockIdx.x * 256 + threadIdx.x;
  if (t < 16384) {
    int k = t >> 7, j = t & 127;
    float acc;
    if (j < 64) {
      acc = 0.f;
      for (int h = 0; h < 64; ++h) acc += wn[k * 64 + h] * wm1[h * 64 + j];
    } else {
      acc = wu1[k * 64 + (j - 64)];
    }
    M[t] = acc;
  } else if (t < 16384 + 2048) {
    int u = t - 16384;
    int k = u >> 6, j = u & 63;
    float acc = 0.f;
    for (int h = 0; h < 64; ++h) acc += we[k * 64 + h] * wm1[(64 + h) * 64 + j];
    B[u] = acc;
  } else if (t < 16384 + 2048 + 64) {
    int j = t - (16384 + 2048);
    float acc = bm1[j];
    for (int h = 0; h < 64; ++h)
      acc += bn[h] * wm1[h * 64 + j] + be[h] * wm1[(64 + h) * 64 + j];
    c[j] = acc;
  } else if (t < 16384 + 2048 + 64 + 4096) {
    int u = t - (16384 + 2048 + 64);
    int k = u >> 6, j = u & 63;
    float acc = 0.f;
    for (int h = 0; h < 64; ++h) acc += wm2[k * 64 + h] * wu1[(128 + h) * 64 + j];
    W2U[u] = acc;
  } else if (t < 16384 + 2048 + 64 + 4096 + 64) {
    int j = t - (16384 + 2048 + 64 + 4096);
    float acc = 0.f;
    for (int h = 0; h < 64; ++h) acc += bm2[h] * wu1[(128 + h) * 64 + j];
    d2[j] = acc;
  }
}

// ---------------------------------------------------------------------------
// PRA[n] = nf[n]@A ; PRU[n] = nf[n]@wu1_top  (lane-per-node, scalar weights)
// ---------------------------------------------------------------------------
__global__ __launch_bounds__(256) void k_node(
    const float* __restrict__ nf, const float* __restrict__ M,
    float* __restrict__ PRA, float* __restrict__ PRU) {
  int n = blockIdx.x * 256 + threadIdx.x;
  if (n >= NN) return;
  const float* __restrict__ row = &nf[(size_t)n * 128];
#pragma unroll 1
  for (int jc = 0; jc < 128; jc += 32) {
    float q[32];
#pragma unroll
    for (int jj = 0; jj < 32; ++jj) q[jj] = 0.f;
#pragma unroll 4
    for (int k = 0; k < 128; k += 4) {
      float4 r4 = *(const float4*)&row[k];
#pragma unroll
      for (int jj = 0; jj < 32; ++jj) q[jj] += r4.x * M[(k + 0) * 128 + jc + jj];
#pragma unroll
      for (int jj = 0; jj < 32; ++jj) q[jj] += r4.y * M[(k + 1) * 128 + jc + jj];
#pragma unroll
      for (int jj = 0; jj < 32; ++jj) q[jj] += r4.z * M[(k + 2) * 128 + jc + jj];
#pragma unroll
      for (int jj = 0; jj < 32; ++jj) q[jj] += r4.w * M[(k + 3) * 128 + jc + jj];
    }
    float* dstp = (jc < 64) ? &PRA[(size_t)n * 64 + jc] : &PRU[(size_t)n * 64 + (jc - 64)];
#pragma unroll
    for (int jj = 0; jj < 32; jj += 4)
      *(float4*)&dstp[jj] = make_float4(q[jj], q[jj + 1], q[jj + 2], q[jj + 3]);
  }
}

// ---------------------------------------------------------------------------
// Counting sort: hist -> 3-phase scan -> scatter {edge,src} pairs
// ---------------------------------------------------------------------------
__global__ __launch_bounds__(256) void k_hist(const int* __restrict__ idx,
                                              int* __restrict__ hist) {
  int e = blockIdx.x * 256 + threadIdx.x;
  if (e < NE) atomicAdd(&hist[idx[NE + e]], 1);
}

__global__ __launch_bounds__(1024) void k_scanA(const int* __restrict__ hist,
                                                int* __restrict__ strt,
                                                int* __restrict__ bsum) {
  __shared__ int lds[1024];
  int t = threadIdx.x;
  int i = blockIdx.x * 1024 + t;
  int v = (i < NN) ? hist[i] : 0;
  lds[t] = v;
  __syncthreads();
  for (int off = 1; off < 1024; off <<= 1) {
    int u = (t >= off) ? lds[t - off] : 0;
    __syncthreads();
    lds[t] += u;
    __syncthreads();
  }
  if (i < NN) strt[i] = lds[t] - v;
  if (t == 1023) bsum[blockIdx.x] = lds[1023];
}

__global__ __launch_bounds__(128) void k_scanB(const int* __restrict__ bsum,
                                               int* __restrict__ boff,
                                               int* __restrict__ strt,
                                               int nblocks) {
  __shared__ int lds[128];
  int t = threadIdx.x;
  int v = (t < nblocks) ? bsum[t] : 0;
  lds[t] = v;
  __syncthreads();
  for (int off = 1; off < 128; off <<= 1) {
    int u = (t >= off) ? lds[t - off] : 0;
    __syncthreads();
    lds[t] += u;
    __syncthreads();
  }
  if (t < nblocks) boff[t] = lds[t] - v;
  if (t == 127) strt[NN] = lds[127];
}

__global__ __launch_bounds__(1024) void k_scanC(int* __restrict__ strt,
                                                const int* __restrict__ boff) {
  int i = blockIdx.x * 1024 + threadIdx.x;
  if (i < NN) strt[i] += boff[blockIdx.x];
}

__global__ __launch_bounds__(256) void k_scatter_pairs2(
    const int* __restrict__ idx, const int* __restrict__ strt,
    int* __restrict__ cursor, int2* __restrict__ esrc) {
  int e = blockIdx.x * 256 + threadIdx.x;
  if (e >= NE) return;
  int dst = idx[NE + e];
  int pos = atomicAdd(&cursor[dst], 1);
  int2 v;
  v.x = e;
  v.y = idx[e];
  esrc[strt[dst] + pos] = v;
}

// ---------------------------------------------------------------------------
// Fused message+aggregate v4 (gather4 structure + depth-2 ping-pong):
// one WAVE per node; edges in PAIRS (lanes 0-31 = edge A, 32-63 = edge B);
// lane owns output dims {2*l5, 2*l5+1}. Register sets X (even pairs) and
// Y (odd pairs): while computing pair b from X, the refill load for pair
// b+2 is issued -> every vector load has ~2 pair-computations of wall time
// to complete. ef relayed through wave-private LDS (no barrier needed).
// ---------------------------------------------------------------------------
#define LOADP(efv, pr2, sidx)                                     \
  {                                                               \
    int2 pa_ = esrc[sidx], pb_ = esrc[(sidx) + 1];                \
    int eA_ = rfl(pa_.x), sA_ = rfl(pa_.y);                       \
    int eB_ = rfl(pb_.x), sB_ = rfl(pb_.y);                       \
    int em_ = half ? eB_ : eA_;                                   \
    int sm_ = half ? sB_ : sA_;                                   \
    efv = ef[(size_t)em_ * 32 + l5];                              \
    pr2 = *(const float2*)&PRA[(size_t)sm_ * 64 + 2 * l5];        \
  }

#define FMA8(bb_, qx, qy)                                         \
  _Pragma("unroll") for (int u = 0; u < 8; ++u) {                 \
    float4 v = *(const float4*)&(bb_)[4 * u];                     \
    qx = fmaf(v.x, Bc[4 * u + 0].x, qx);                          \
    qy = fmaf(v.x, Bc[4 * u + 0].y, qy);                          \
    qx = fmaf(v.y, Bc[4 * u + 1].x, qx);                          \
    qy = fmaf(v.y, Bc[4 * u + 1].y, qy);                          \
    qx = fmaf(v.z, Bc[4 * u + 2].x, qx);                          \
    qy = fmaf(v.z, Bc[4 * u + 2].y, qy);                          \
    qx = fmaf(v.w, Bc[4 * u + 3].x, qx);                          \
    qy = fmaf(v.w, Bc[4 * u + 3].y, qy);                          \
  }

__global__ __launch_bounds__(256) void k_gather6(
    const int2* __restrict__ esrc, const int* __restrict__ strt,
    const float* __restrict__ ef, const float* __restrict__ Bm,
    const float* __restrict__ c, const float* __restrict__ PRA,
    float* __restrict__ H) {
  __shared__ float efb[4][2][2][32];  // [wave][slot X/Y][half][k]
  int wib = threadIdx.x >> 6;
  int lane = threadIdx.x & 63;
  int half = lane >> 5;
  int l5 = lane & 31;
  int n = rfl(blockIdx.x * 4 + wib);
  if (n >= NN) return;

  float2 Bc[32];
#pragma unroll
  for (int k = 0; k < 32; ++k) Bc[k] = *(const float2*)&Bm[k * 64 + 2 * l5];
  float clx = c[2 * l5], cly = c[2 * l5 + 1];

  int s0 = rfl(strt[n]);
  int s1 = rfl(strt[n + 1]);
  int np = (s1 - s0) >> 1;

  float accx = 0.f, accy = 0.f;

  float efX = 0.f, efY = 0.f;
  float2 prX = make_float2(0.f, 0.f), prY = make_float2(0.f, 0.f);

  if (np > 0) LOADP(efX, prX, s0);
  if (np > 1) LOADP(efY, prY, s0 + 2);

  int b = 0;
#pragma unroll 1
  while (b < np) {
    // ---- compute pair b from X; refill X with pair b+2 ----
    {
      float pcx = prX.x, pcy = prX.y;
      float* bufX = &efb[wib][0][0][0];
      bufX[half * 32 + l5] = efX;           // stage (reads old efX)
      if (b + 2 < np) LOADP(efX, prX, s0 + 2 * (b + 2));
      const float* bbX = &efb[wib][0][half][0];
      float qx = clx, qy = cly;
      FMA8(bbX, qx, qy);
      accx += fmaxf(qx + pcx, 0.f);
      accy += fmaxf(qy + pcy, 0.f);
    }
    if (++b >= np) break;
    // ---- compute pair b (odd) from Y; refill Y with pair b+2 ----
    {
      float pcx = prY.x, pcy = prY.y;
      float* bufY = &efb[wib][1][0][0];
      bufY[half * 32 + l5] = efY;
      if (b + 2 < np) LOADP(efY, prY, s0 + 2 * (b + 2));
      const float* bbY = &efb[wib][1][half][0];
      float qx = clx, qy = cly;
      FMA8(bbY, qx, qy);
      accx += fmaxf(qx + pcx, 0.f);
      accy += fmaxf(qy + pcy, 0.f);
    }
    ++b;
  }

  // tail: odd remaining edge, half 0 accumulates only
  if ((s1 - s0) & 1) {
    int2 es = esrc[s1 - 1];
    int e = rfl(es.x), sr = rfl(es.y);
    const float* __restrict__ efp = &ef[(size_t)e * 32];
    float qx = clx, qy = cly;
#pragma unroll
    for (int u = 0; u < 8; ++u) {
      float4 v = *(const float4*)&efp[4 * u];
      qx = fmaf(v.x, Bc[4 * u + 0].x, qx); qy = fmaf(v.x, Bc[4 * u + 0].y, qy);
      qx = fmaf(v.y, Bc[4 * u + 1].x, qx); qy = fmaf(v.y, Bc[4 * u + 1].y, qy);
      qx = fmaf(v.z, Bc[4 * u + 2].x, qx); qy = fmaf(v.z, Bc[4 * u + 2].y, qy);
      qx = fmaf(v.w, Bc[4 * u + 3].x, qx); qy = fmaf(v.w, Bc[4 * u + 3].y, qy);
    }
    float2 p2 = *(const float2*)&PRA[(size_t)sr * 64 + 2 * l5];
    float rx = fmaxf(qx + p2.x, 0.f), ry = fmaxf(qy + p2.y, 0.f);
    if (half == 0) { accx += rx; accy += ry; }
  }

  // combine halves and store
  accx += __shfl_xor(accx, 32);
  accy += __shfl_xor(accy, 32);
  if (half == 0)
    *(float2*)&H[(size_t)n * 64 + 2 * l5] = make_float2(accx, accy);
}

// ---------------------------------------------------------------------------
// Final per-node MLP with W2U fold:
//   pre = PRU[n] + H[n]@W2U + deg*d2 + bu1 ; out = relu(pre)@wu2 + bu2
// ---------------------------------------------------------------------------
__global__ __launch_bounds__(256) void k_update3(
    const float* __restrict__ H, const int* __restrict__ strt,
    const float* __restrict__ PRU,
    const float* __restrict__ W2U, const float* __restrict__ d2,
    const float* __restrict__ bu1,
    const float* __restrict__ wu2, const float* __restrict__ bu2,
    float* __restrict__ out) {
  int n = blockIdx.x * 256 + threadIdx.x;
  if (n >= NN) return;

  float Hr[64];
#pragma unroll
  for (int k = 0; k < 64; k += 4)
    *(float4*)&Hr[k] = *(const float4*)&H[(size_t)n * 64 + k];
  float deg = (float)(strt[n + 1] - strt[n]);

  float acc[64];
#pragma unroll
  for (int o = 0; o < 64; ++o) acc[o] = bu2[o];

  const float* __restrict__ prs = &PRU[(size_t)n * 64];
#pragma unroll 1
  for (int jc = 0; jc < 64; jc += 16) {
    float q[16];
#pragma unroll
    for (int jj = 0; jj < 16; ++jj) q[jj] = bu1[jc + jj] + deg * d2[jc + jj];
#pragma unroll
    for (int k = 0; k < 64; ++k) {
      float hv = Hr[k];
#pragma unroll
      for (int jj = 0; jj < 16; ++jj) q[jj] += hv * W2U[k * 64 + jc + jj];
    }
#pragma unroll
    for (int jj = 0; jj < 16; ++jj) {
      float h = fmaxf(prs[jc + jj] + q[jj], 0.f);
#pragma unroll
      for (int o = 0; o < 64; ++o) acc[o] += h * wu2[(jc + jj) * 64 + o];
    }
  }

#pragma unroll
  for (int o = 0; o < 64; o += 4)
    *(float4*)&out[(size_t)n * 64 + o] = make_float4(acc[o], acc[o + 1], acc[o + 2], acc[o + 3]);
}

// ---------------------------------------------------------------------------
// Fallback (ws too small): round-1 atomic scatter path
// ---------------------------------------------------------------------------
__global__ __launch_bounds__(256) void k_edge_at(
    const int* __restrict__ idx, const float* __restrict__ ef,
    const float* __restrict__ B, const float* __restrict__ c,
    const float* __restrict__ wm2, const float* __restrict__ bm2,
    const float* __restrict__ PRA, float* __restrict__ agg) {
  int e = blockIdx.x * 256 + threadIdx.x;
  if (e >= NE) return;
  int src = idx[e];
  int dst = idx[NE + e];
  float efr[32];
#pragma unroll
  for (int k = 0; k < 32; k += 4)
    *(float4*)&efr[k] = *(const float4*)&ef[(size_t)e * 32 + k];
  float m[64];
#pragma unroll
  for (int o = 0; o < 64; ++o) m[o] = bm2[o];
  const float* __restrict__ prs = &PRA[(size_t)src * 64];
#pragma unroll 1
  for (int jc = 0; jc < 64; jc += 16) {
    float q[16];
#pragma unroll
    for (int jj = 0; jj < 16; ++jj) q[jj] = c[jc + jj];
#pragma unroll
    for (int k = 0; k < 32; ++k) {
      float ev = efr[k];
#pragma unroll
      for (int jj = 0; jj < 16; ++jj) q[jj] += ev * B[k * 64 + jc + jj];
    }
#pragma unroll
    for (int jj = 0; jj < 16; ++jj) {
      float h = fmaxf(prs[jc + jj] + q[jj], 0.f);
#pragma unroll
      for (int o = 0; o < 64; ++o) m[o] += h * wm2[(jc + jj) * 64 + o];
    }
  }
  float* __restrict__ ap = &agg[(size_t)dst * 64];
#pragma unroll
  for (int o = 0; o < 64; ++o) atomicAdd(&ap[o], m[o]);
}

__global__ __launch_bounds__(256) void k_update_at(
    const float* __restrict__ agg, const float* __restrict__ PRU,
    const float* __restrict__ wu1, const float* __restrict__ bu1,
    const float* __restrict__ wu2, const float* __restrict__ bu2,
    float* __restrict__ out) {
  int n = blockIdx.x * 256 + threadIdx.x;
  if (n >= NN) return;
  float ar[64];
#pragma unroll
  for (int k = 0; k < 64; k += 4)
    *(float4*)&ar[k] = *(const float4*)&agg[(size_t)n * 64 + k];
  float acc[64];
#pragma unroll
  for (int o = 0; o < 64; ++o) acc[o] = bu2[o];
  const float* __restrict__ prs = &PRU[(size_t)n * 64];
#pragma unroll 1
  for (int jc = 0; jc < 64; jc += 16) {
    float q[16];
#pragma unroll
    for (int jj = 0; jj < 16; ++jj) q[jj] = bu1[jc + jj];
#pragma unroll
    for (int k = 0; k < 64; ++k) {
      float av = ar[k];
#pragma unroll
      for (int jj = 0; jj < 16; ++jj) q[jj] += av * wu1[(128 + k) * 64 + jc + jj];
    }
#pragma unroll
    for (int jj = 0; jj < 16; ++jj) {
      float h = fmaxf(prs[jc + jj] + q[jj], 0.f);
#pragma unroll
      for (int o = 0; o < 64; ++o) acc[o] += h * wu2[(jc + jj) * 64 + o];
    }
  }
#pragma unroll
  for (int o = 0; o < 64; o += 4)
    *(float4*)&out[(size_t)n * 64 + o] = make_float4(acc[o], acc[o + 1], acc[o + 2], acc[o + 3]);
}

extern "C" void kernel_launch(void* const* d_in, const int* in_sizes, int n_in,
                              void* d_out, int out_size, void* d_ws, size_t ws_size,
                              hipStream_t stream) {
  const float* nf  = (const float*)d_in[0];
  const int*   idx = (const int*)d_in[1];
  const float* ef  = (const float*)d_in[2];
  const float* wn  = (const float*)d_in[3];
  const float* bn  = (const float*)d_in[4];
  const float* we  = (const float*)d_in[5];
  const float* be  = (const float*)d_in[6];
  const float* wm1 = (const float*)d_in[7];
  const float* bm1 = (const float*)d_in[8];
  const float* wm2 = (const float*)d_in[9];
  const float* bm2 = (const float*)d_in[10];
  const float* wu1 = (const float*)d_in[11];
  const float* bu1 = (const float*)d_in[12];
  const float* wu2 = (const float*)d_in[13];
  const float* bu2 = (const float*)d_in[14];
  float* out = (float*)d_out;

  float* ws   = (float*)d_ws;
  float* M    = ws + OFF_M;
  float* B    = ws + OFF_B;
  float* c    = ws + OFF_C;
  float* W2U  = ws + OFF_W2U;
  float* d2   = ws + OFF_D2;
  int*   bsum = (int*)(ws + OFF_BSUM);
  int*   boff = (int*)(ws + OFF_BOFF);
  float* PRA  = ws + OFF_PRA;
  float* PRU  = ws + OFF_PRU;
  float* H    = ws + OFF_H;
  int*   hist = (int*)(ws + OFF_HIST);
  int*   cur  = (int*)(ws + OFF_CUR);
  int*   strt = (int*)(ws + OFF_STRT);
  int2*  esrc = (int2*)(ws + OFF_ESRC);

  const int SCAN_BLOCKS = (NN + 1023) / 1024;  // 98

  k_fold<<<(16384 + 2048 + 64 + 4096 + 64 + 255) / 256, 256, 0, stream>>>(
      wn, bn, we, be, wm1, bm1, wm2, bm2, wu1, M, B, c, W2U, d2);
  k_node<<<(NN + 255) / 256, 256, 0, stream>>>(nf, M, PRA, PRU);

  if (ws_size >= (size_t)WS_UNITS * 4) {
    hipMemsetAsync(hist, 0, (size_t)2 * NN * sizeof(int), stream);
    k_hist<<<(NE + 255) / 256, 256, 0, stream>>>(idx, hist);
    k_scanA<<<SCAN_BLOCKS, 1024, 0, stream>>>(hist, strt, bsum);
    k_scanB<<<1, 128, 0, stream>>>(bsum, boff, strt, SCAN_BLOCKS);
    k_scanC<<<SCAN_BLOCKS, 1024, 0, stream>>>(strt, boff);
    k_scatter_pairs2<<<(NE + 255) / 256, 256, 0, stream>>>(idx, strt, cur, esrc);
    k_gather6<<<(NN + 3) / 4, 256, 0, stream>>>(esrc, strt, ef, B, c, PRA, H);
    k_update3<<<(NN + 255) / 256, 256, 0, stream>>>(
        H, strt, PRU, W2U, d2, bu1, wu2, bu2, out);
  } else {
    hipMemsetAsync(H, 0, (size_t)NN * 64 * sizeof(float), stream);
    k_edge_at<<<(NE + 255) / 256, 256, 0, stream>>>(idx, ef, B, c, wm2, bm2, PRA, H);
    k_update_at<<<(NN + 255) / 256, 256, 0, stream>>>(
        H, PRU, wu1, bu1, wu2, bu2, out);
  }
}